// Round 1
// baseline (238.851 us; speedup 1.0000x reference)
//
#include <hip/hip_runtime.h>
#include <math.h>

#define NN_ 2048
#define CC_ 256
#define KC_ 128
#define KF_ 16
#define EQCAP 64

__device__ __forceinline__ unsigned int mono_u(float f) {
  unsigned int u = __float_as_uint(f);
  return (u & 0x80000000u) ? ~u : (u | 0x80000000u);
}

// C[m,n] = sum_k A[m,k]*Bm[n,k] + bias[n]   (A: MxK, Bm: NxK, both row-major)
__global__ __launch_bounds__(256) void gemm_abt_kernel(
    const float* __restrict__ A, const float* __restrict__ Bm,
    const float* __restrict__ bias, float* __restrict__ C,
    int M, int N, int K, long sA, long sB, long sC)
{
  constexpr int BK = 32;
  __shared__ float As[BK][64];
  __shared__ float Bs[BK][64];
  const int z = blockIdx.z;
  A += (long)z * sA; Bm += (long)z * sB; C += (long)z * sC;
  const int m0 = blockIdx.y * 64, n0 = blockIdx.x * 64;
  const int tid = threadIdx.x;
  const int tx = tid & 15, ty = tid >> 4;
  float acc[4][4] = {};
  for (int kb = 0; kb < K; kb += BK) {
#pragma unroll
    for (int l = 0; l < 2; ++l) {
      int i = tid + l * 256;
      int r = i >> 3;
      int c4 = (i & 7) << 2;
      float4 va = *(const float4*)(A + (long)(m0 + r) * K + kb + c4);
      As[c4 + 0][r] = va.x; As[c4 + 1][r] = va.y;
      As[c4 + 2][r] = va.z; As[c4 + 3][r] = va.w;
      float4 vb = *(const float4*)(Bm + (long)(n0 + r) * K + kb + c4);
      Bs[c4 + 0][r] = vb.x; Bs[c4 + 1][r] = vb.y;
      Bs[c4 + 2][r] = vb.z; Bs[c4 + 3][r] = vb.w;
    }
    __syncthreads();
#pragma unroll
    for (int kk = 0; kk < BK; ++kk) {
      float a[4], b[4];
      *(float4*)a = *(const float4*)&As[kk][ty << 2];
      *(float4*)b = *(const float4*)&Bs[kk][tx << 2];
#pragma unroll
      for (int i = 0; i < 4; ++i)
#pragma unroll
        for (int j = 0; j < 4; ++j)
          acc[i][j] += a[i] * b[j];
    }
    __syncthreads();
  }
  float bv[4] = {0.f, 0.f, 0.f, 0.f};
  if (bias) {
#pragma unroll
    for (int j = 0; j < 4; ++j) bv[j] = bias[n0 + (tx << 2) + j];
  }
#pragma unroll
  for (int i = 0; i < 4; ++i) {
    int m = m0 + (ty << 2) + i;
    float4 v;
    v.x = acc[i][0] + bv[0];
    v.y = acc[i][1] + bv[1];
    v.z = acc[i][2] + bv[2];
    v.w = acc[i][3] + bv[3];
    *(float4*)(C + (long)m * N + n0 + (tx << 2)) = v;
  }
}

// One block (256 threads) per output row: exact top-128 (radix select, jax tie
// semantics = lowest index among equals), angular mask with all-true fallback,
// fine top-16 (value desc, orig index asc), softmax, zero+scatter+writeback.
__global__ __launch_bounds__(256) void select_scatter_kernel(
    const float* __restrict__ sim, const float* __restrict__ dirs_a,
    const float* __restrict__ dirs_b, float* __restrict__ P)
{
  const int row = blockIdx.x;          // b*N + n
  const int b = row >> 11;             // N = 2048
  const int tid = threadIdx.x;
  const float* srow = sim + (long)row * NN_;
  float* prow = P + (long)row * NN_;

  __shared__ float sv[NN_];
  __shared__ unsigned int hist[256];
  __shared__ unsigned int sscan[256];
  __shared__ int cand[KC_];
  __shared__ float cvalv[KC_];
  __shared__ int cmaskv[KC_];
  __shared__ int eqbuf[EQCAP];
  __shared__ int selbin, selneed, ncand, neq, ecnt, nkeep_s;
  __shared__ float outp[KF_];
  __shared__ int outj[KF_];

  // sim row -> LDS (coalesced float4)
  for (int i = tid; i < NN_ / 4; i += 256)
    *(float4*)&sv[i << 2] = *(const float4*)(srow + (i << 2));
  __syncthreads();

  // ---- radix select threshold of the 128th-largest value ----
  unsigned int prefix = 0u, pmask = 0u;
  int need = KC_;
  for (int pass = 0; pass < 4; ++pass) {
    const int s = 24 - pass * 8;
    hist[tid] = 0u;
    __syncthreads();
#pragma unroll
    for (int i = 0; i < 8; ++i) {
      unsigned int u = mono_u(sv[tid + (i << 8)]);
      if ((u & pmask) == prefix) atomicAdd(&hist[(u >> s) & 255u], 1u);
    }
    __syncthreads();
    sscan[tid] = hist[tid];
    __syncthreads();
    for (int off = 1; off < 256; off <<= 1) {
      unsigned int v = (tid + off < 256) ? sscan[tid + off] : 0u;
      __syncthreads();
      sscan[tid] += v;
      __syncthreads();
    }
    unsigned int geq = sscan[tid];
    unsigned int gt = (tid < 255) ? sscan[tid + 1] : 0u;
    if (geq >= (unsigned)need && gt < (unsigned)need) {
      selbin = tid;
      selneed = need - (int)gt;
    }
    __syncthreads();
    prefix |= ((unsigned)selbin) << s;
    pmask |= 0xFFu << s;
    need = selneed;
    __syncthreads();
  }
  const unsigned int T = prefix;
  const int need_eq = need;
  const int count_gt = KC_ - need_eq;

  if (tid == 0) { ncand = 0; neq = 0; ecnt = 0; }
  __syncthreads();
  // strictly-greater (membership only; order irrelevant) + equals (need index order)
#pragma unroll
  for (int i = 0; i < 8; ++i) {
    int j = tid + (i << 8);
    unsigned int u = mono_u(sv[j]);
    if (u > T) {
      int p = atomicAdd(&ncand, 1);
      cand[p] = j;
    } else if (u == T) {
      int p = atomicAdd(&neq, 1);
      if (p < EQCAP) eqbuf[p] = j;
    }
  }
  __syncthreads();
  if (tid == 0) {
    int m = neq;
    if (m <= EQCAP) {  // typical: m == 1
      for (int r = 0; r < need_eq; ++r) {
        int best = 0x7FFFFFFF, bi = 0;
        for (int t2 = 0; t2 < m; ++t2)
          if (eqbuf[t2] < best) { best = eqbuf[t2]; bi = t2; }
        eqbuf[bi] = 0x7FFFFFFF;
        cand[count_gt + r] = best;
      }
    } else {  // pathological mass-tie fallback: scan row in index order
      int r = 0;
      for (int j = 0; j < NN_ && r < need_eq; ++j)
        if (mono_u(sv[j]) == T) cand[count_gt + (r++)] = j;
    }
  }
  __syncthreads();

  // ---- candidate values + angular locality mask ----
  const long dbase = (long)row * 3;
  const float dax = dirs_a[dbase + 0], day = dirs_a[dbase + 1],
              daz = dirs_a[dbase + 2];
  if (tid < KC_) {
    int j = cand[tid];
    cvalv[tid] = sv[j];
    const float* db = dirs_b + ((long)b * NN_ + j) * 3;
    float ca = dax * db[0] + day * db[1] + daz * db[2];
    // ang <= radians(15)  <=>  cosang >= cos(radians(15))
    int loc = (ca >= 0.96592582628906831f) ? 1 : 0;
    cmaskv[tid] = loc;
    if (loc) atomicAdd(&ecnt, 1);
  }
  __syncthreads();

  // ---- fine top-16 + softmax, wave 0 only ----
  if (tid < 64) {
    const bool all = (ecnt == 0);  // coarse fallback: mask empty -> all eligible
    float v0 = (all || cmaskv[tid]) ? cvalv[tid] : -INFINITY;
    float v1 = (all || cmaskv[tid + 64]) ? cvalv[tid + 64] : -INFINITY;
    int j0 = cand[tid], j1 = cand[tid + 64];
    const int elig = all ? KC_ : ecnt;
    const int nk = elig < KF_ ? elig : KF_;
    if (tid == 0) nkeep_s = nk;
    for (int r = 0; r < nk; ++r) {
      float bvv; int bj; int bs;
      if (v1 > v0 || (v1 == v0 && j1 < j0)) { bvv = v1; bj = j1; bs = tid + 64; }
      else { bvv = v0; bj = j0; bs = tid; }
#pragma unroll
      for (int off = 32; off > 0; off >>= 1) {
        float ov = __shfl_down(bvv, off);
        int oj = __shfl_down(bj, off);
        int os = __shfl_down(bs, off);
        if (ov > bvv || (ov == bvv && oj < bj)) { bvv = ov; bj = oj; bs = os; }
      }
      bvv = __shfl(bvv, 0); bj = __shfl(bj, 0); bs = __shfl(bs, 0);
      if (tid == 0) { outj[r] = bj; outp[r] = bvv; }
      if (bs == tid) v0 = -INFINITY;
      if (bs == tid + 64) v1 = -INFINITY;
    }
    if (tid == 0) {
      // softmax over kept logits (NEG-filled fine slots contribute exactly 0)
      float mx = -INFINITY;
      for (int r = 0; r < nk; ++r) mx = fmaxf(mx, outp[r] / 0.07f);
      float e[KF_];
      float ssum = 0.f;
      for (int r = 0; r < nk; ++r) {
        e[r] = expf(outp[r] / 0.07f - mx);
        ssum += e[r];
      }
      float s2 = 0.f;
      for (int r = 0; r < nk; ++r) { e[r] = e[r] / ssum; s2 += e[r]; }
      float inv = 1.0f / (s2 + 1e-8f);
      for (int r = 0; r < nk; ++r) outp[r] = e[r] * inv;
    }
  }
  __syncthreads();

  // ---- zero + scatter in LDS, then coalesced writeback ----
  for (int i = tid; i < NN_; i += 256) sv[i] = 0.f;
  __syncthreads();
  if (tid < nkeep_s) sv[outj[tid]] = outp[tid];
  __syncthreads();
  for (int i = tid; i < NN_ / 4; i += 256)
    *(float4*)(prow + (i << 2)) = *(const float4*)&sv[i << 2];
}

extern "C" void kernel_launch(void* const* d_in, const int* in_sizes, int n_in,
                              void* d_out, int out_size, void* d_ws, size_t ws_size,
                              hipStream_t stream) {
  (void)in_sizes; (void)n_in; (void)out_size; (void)ws_size;
  const float* feat_a = (const float*)d_in[0];   // [2,2048,256]
  const float* feat_b = (const float*)d_in[1];   // [2,2048,256]
  const float* dirs_a = (const float*)d_in[2];   // [2,2048,3]
  const float* dirs_b = (const float*)d_in[3];   // [2,2048,3]
  const float* Wq = (const float*)d_in[4];       // [256,256]
  const float* bq = (const float*)d_in[5];       // [256]
  const float* Wk = (const float*)d_in[6];       // [256,256]
  const float* bk = (const float*)d_in[7];       // [256]
  float* P = (float*)d_out;                      // [2,2048,2048]

  float* q = (float*)d_ws;                       // 4096x256
  float* k = q + (long)2 * NN_ * CC_;            // 4096x256
  float* sim = k + (long)2 * NN_ * CC_;          // 2x2048x2048

  const int MQK = 2 * NN_;  // 4096 rows

  // q = feat_a @ Wq^T + bq ; k = feat_b @ Wk^T + bk
  gemm_abt_kernel<<<dim3(CC_ / 64, MQK / 64, 1), 256, 0, stream>>>(
      feat_a, Wq, bq, q, MQK, CC_, CC_, 0, 0, 0);
  gemm_abt_kernel<<<dim3(CC_ / 64, MQK / 64, 1), 256, 0, stream>>>(
      feat_b, Wk, bk, k, MQK, CC_, CC_, 0, 0, 0);

  // sim[b] = q[b] @ k[b]^T
  gemm_abt_kernel<<<dim3(NN_ / 64, NN_ / 64, 2), 256, 0, stream>>>(
      q, k, nullptr, sim, NN_, NN_, CC_,
      (long)NN_ * CC_, (long)NN_ * CC_, (long)NN_ * NN_);

  // per-row coarse/fine selection + softmax + scatter
  select_scatter_kernel<<<dim3(2 * NN_), 256, 0, stream>>>(sim, dirs_a, dirs_b, P);
}

// Round 2
// 182.818 us; speedup vs baseline: 1.3065x; 1.3065x over previous
//
#include <hip/hip_runtime.h>
#include <hip/hip_bf16.h>
#include <math.h>

#define NN_ 2048
#define CC_ 256
#define KC_ 128
#define KF_ 16
#define EQCAP 64

typedef __attribute__((ext_vector_type(8))) short short8;
typedef __attribute__((ext_vector_type(4))) float f32x4;

__device__ __forceinline__ unsigned int mono_u(float f) {
  unsigned int u = __float_as_uint(f);
  return (u & 0x80000000u) ? ~u : (u | 0x80000000u);
}

__device__ __forceinline__ void gload_lds16(const void* g, void* l) {
  __builtin_amdgcn_global_load_lds(
      (const __attribute__((address_space(1))) void*)g,
      (__attribute__((address_space(3))) void*)l, 16, 0, 0);
}

// Fused projection: z=0 -> q = feat_a@Wq^T+bq, split into (qh,ql) bf16
//                   z=1 -> k = feat_b@Wk^T+bk, split into (kh,kl) bf16
// fp32 64x64 tile core (exactness of q/k matters at fp32 level).
__global__ __launch_bounds__(256) void proj_split_kernel(
    const float* __restrict__ fa, const float* __restrict__ fb,
    const float* __restrict__ Wq, const float* __restrict__ bq,
    const float* __restrict__ Wk, const float* __restrict__ bk,
    __hip_bfloat16* __restrict__ qh, __hip_bfloat16* __restrict__ ql,
    __hip_bfloat16* __restrict__ kh, __hip_bfloat16* __restrict__ kl)
{
  constexpr int BK = 32;
  __shared__ float As[BK][64];
  __shared__ float Bs[BK][64];
  const int z = blockIdx.z;
  const float* A = z ? fb : fa;
  const float* W = z ? Wk : Wq;
  const float* bias = z ? bk : bq;
  __hip_bfloat16* oh = z ? kh : qh;
  __hip_bfloat16* ol = z ? kl : ql;

  const int m0 = blockIdx.y * 64, n0 = blockIdx.x * 64;
  const int tid = threadIdx.x;
  const int tx = tid & 15, ty = tid >> 4;
  float acc[4][4] = {};
  for (int kb = 0; kb < CC_; kb += BK) {
#pragma unroll
    for (int l = 0; l < 2; ++l) {
      int i = tid + l * 256;
      int r = i >> 3;
      int c4 = (i & 7) << 2;
      float4 va = *(const float4*)(A + (long)(m0 + r) * CC_ + kb + c4);
      As[c4 + 0][r] = va.x; As[c4 + 1][r] = va.y;
      As[c4 + 2][r] = va.z; As[c4 + 3][r] = va.w;
      float4 vb = *(const float4*)(W + (long)(n0 + r) * CC_ + kb + c4);
      Bs[c4 + 0][r] = vb.x; Bs[c4 + 1][r] = vb.y;
      Bs[c4 + 2][r] = vb.z; Bs[c4 + 3][r] = vb.w;
    }
    __syncthreads();
#pragma unroll
    for (int kk = 0; kk < BK; ++kk) {
      float a[4], b[4];
      *(float4*)a = *(const float4*)&As[kk][ty << 2];
      *(float4*)b = *(const float4*)&Bs[kk][tx << 2];
#pragma unroll
      for (int i = 0; i < 4; ++i)
#pragma unroll
        for (int j = 0; j < 4; ++j)
          acc[i][j] += a[i] * b[j];
    }
    __syncthreads();
  }
  float bv[4];
#pragma unroll
  for (int j = 0; j < 4; ++j) bv[j] = bias[n0 + (tx << 2) + j];
#pragma unroll
  for (int i = 0; i < 4; ++i) {
    int m = m0 + (ty << 2) + i;
    __hip_bfloat16 hv[4], lv[4];
#pragma unroll
    for (int j = 0; j < 4; ++j) {
      float v = acc[i][j] + bv[j];
      __hip_bfloat16 h = __float2bfloat16(v);  // RNE
      hv[j] = h;
      lv[j] = __float2bfloat16(v - __bfloat162float(h));
    }
    long base = (long)m * CC_ + n0 + (tx << 2);
    *(uint2*)(oh + base) = *(const uint2*)hv;
    *(uint2*)(ol + base) = *(const uint2*)lv;
  }
}

// sim[z] = qh@kh^T + qh@kl^T + ql@kh^T  (fp32-accurate split-bf16 product)
// 128x128 block tile, 4 waves x (4x4) mfma_f32_16x16x32_bf16, BK=32,
// global_load_lds width-16 staging, XOR chunk-swizzled LDS tile
// (slot(m,chunk) = m*4 + (chunk ^ ((m>>1)&3)), 16B slots -> 2-way banks, free).
__global__ __launch_bounds__(256) void sim_mfma_kernel(
    const __hip_bfloat16* __restrict__ qh, const __hip_bfloat16* __restrict__ ql,
    const __hip_bfloat16* __restrict__ kh, const __hip_bfloat16* __restrict__ kl,
    float* __restrict__ sim)
{
  __shared__ short As[128 * 32];  // 8 KB
  __shared__ short Bs[128 * 32];  // 8 KB
  const int z = blockIdx.z;
  const long off = (long)z * NN_ * CC_;
  const __hip_bfloat16* Aseg[3] = {qh + off, qh + off, ql + off};
  const __hip_bfloat16* Bseg[3] = {kh + off, kl + off, kh + off};
  const int m0 = blockIdx.y * 128, n0 = blockIdx.x * 128;
  const int tid = threadIdx.x;
  const int lane = tid & 63, wave = tid >> 6;
  const int wm = (wave & 1) << 6, wn = (wave >> 1) << 6;
  const int fm = lane & 15, quad = lane >> 4;

  // staging addresses (two 16B issues per thread per tile)
  const int r0 = tid >> 2, r1 = r0 + 64;
  const int c0 = (((tid & 3) ^ ((r0 >> 1) & 3)) << 3);  // element col
  const int c1 = (((tid & 3) ^ ((r1 >> 1) & 3)) << 3);
  short* lA0 = As + (long)tid * 8;
  short* lA1 = As + ((long)tid + 256) * 8;
  short* lB0 = Bs + (long)tid * 8;
  short* lB1 = Bs + ((long)tid + 256) * 8;
  const long gA0 = (long)(m0 + r0) * CC_ + c0;
  const long gA1 = (long)(m0 + r1) * CC_ + c1;
  const long gB0 = (long)(n0 + r0) * CC_ + c0;
  const long gB1 = (long)(n0 + r1) * CC_ + c1;

  f32x4 acc[4][4];
#pragma unroll
  for (int i = 0; i < 4; ++i)
#pragma unroll
    for (int j = 0; j < 4; ++j)
      acc[i][j] = (f32x4){0.f, 0.f, 0.f, 0.f};

  for (int s = 0; s < 3; ++s) {
    const __hip_bfloat16* Ap = Aseg[s];
    const __hip_bfloat16* Bp = Bseg[s];
    for (int kb = 0; kb < CC_; kb += 32) {
      gload_lds16(Ap + gA0 + kb, lA0);
      gload_lds16(Ap + gA1 + kb, lA1);
      gload_lds16(Bp + gB0 + kb, lB0);
      gload_lds16(Bp + gB1 + kb, lB1);
      __syncthreads();
      short8 af[4], bf[4];
#pragma unroll
      for (int t = 0; t < 4; ++t) {
        int m = wm + (t << 4) + fm;
        af[t] = *(const short8*)&As[((m << 2) + (quad ^ ((m >> 1) & 3))) << 3];
        int n = wn + (t << 4) + fm;
        bf[t] = *(const short8*)&Bs[((n << 2) + (quad ^ ((n >> 1) & 3))) << 3];
      }
#pragma unroll
      for (int mi = 0; mi < 4; ++mi)
#pragma unroll
        for (int ni = 0; ni < 4; ++ni)
          acc[mi][ni] = __builtin_amdgcn_mfma_f32_16x16x32_bf16(
              af[mi], bf[ni], acc[mi][ni], 0, 0, 0);
      __syncthreads();
    }
  }

  // C/D layout (verified m89/m91): col = lane&15, row = quad*4 + reg
  float* Cp = sim + (long)z * NN_ * NN_;
#pragma unroll
  for (int mi = 0; mi < 4; ++mi) {
#pragma unroll
    for (int ni = 0; ni < 4; ++ni) {
      int m = m0 + wm + (mi << 4) + (quad << 2);
      int n = n0 + wn + (ni << 4) + fm;
      float* p = Cp + (long)m * NN_ + n;
      p[0] = acc[mi][ni][0];
      p[NN_] = acc[mi][ni][1];
      p[2 * NN_] = acc[mi][ni][2];
      p[3 * NN_] = acc[mi][ni][3];
    }
  }
}

// One block (256 threads) per output row: exact top-128 (radix select, jax tie
// semantics = lowest index among equals), angular mask with all-true fallback,
// fine top-16 (value desc, orig index asc), softmax, zero+scatter+writeback.
__global__ __launch_bounds__(256) void select_scatter_kernel(
    const float* __restrict__ sim, const float* __restrict__ dirs_a,
    const float* __restrict__ dirs_b, float* __restrict__ P)
{
  const int row = blockIdx.x;          // b*N + n
  const int b = row >> 11;             // N = 2048
  const int tid = threadIdx.x;
  const float* srow = sim + (long)row * NN_;
  float* prow = P + (long)row * NN_;

  __shared__ float sv[NN_];
  __shared__ unsigned int hist[256];
  __shared__ unsigned int sscan[256];
  __shared__ int cand[KC_];
  __shared__ float cvalv[KC_];
  __shared__ int cmaskv[KC_];
  __shared__ int eqbuf[EQCAP];
  __shared__ int selbin, selneed, ncand, neq, ecnt, nkeep_s;
  __shared__ float outp[KF_];
  __shared__ int outj[KF_];

  for (int i = tid; i < NN_ / 4; i += 256)
    *(float4*)&sv[i << 2] = *(const float4*)(srow + (i << 2));
  __syncthreads();

  // ---- radix select threshold of the 128th-largest value ----
  unsigned int prefix = 0u, pmask = 0u;
  int need = KC_;
  for (int pass = 0; pass < 4; ++pass) {
    const int s = 24 - pass * 8;
    hist[tid] = 0u;
    __syncthreads();
#pragma unroll
    for (int i = 0; i < 8; ++i) {
      unsigned int u = mono_u(sv[tid + (i << 8)]);
      if ((u & pmask) == prefix) atomicAdd(&hist[(u >> s) & 255u], 1u);
    }
    __syncthreads();
    sscan[tid] = hist[tid];
    __syncthreads();
    for (int off = 1; off < 256; off <<= 1) {
      unsigned int v = (tid + off < 256) ? sscan[tid + off] : 0u;
      __syncthreads();
      sscan[tid] += v;
      __syncthreads();
    }
    unsigned int geq = sscan[tid];
    unsigned int gt = (tid < 255) ? sscan[tid + 1] : 0u;
    if (geq >= (unsigned)need && gt < (unsigned)need) {
      selbin = tid;
      selneed = need - (int)gt;
    }
    __syncthreads();
    prefix |= ((unsigned)selbin) << s;
    pmask |= 0xFFu << s;
    need = selneed;
    __syncthreads();
  }
  const unsigned int T = prefix;
  const int need_eq = need;
  const int count_gt = KC_ - need_eq;

  if (tid == 0) { ncand = 0; neq = 0; ecnt = 0; }
  __syncthreads();
#pragma unroll
  for (int i = 0; i < 8; ++i) {
    int j = tid + (i << 8);
    unsigned int u = mono_u(sv[j]);
    if (u > T) {
      int p = atomicAdd(&ncand, 1);
      cand[p] = j;
    } else if (u == T) {
      int p = atomicAdd(&neq, 1);
      if (p < EQCAP) eqbuf[p] = j;
    }
  }
  __syncthreads();
  if (tid == 0) {
    int m = neq;
    if (m <= EQCAP) {
      for (int r = 0; r < need_eq; ++r) {
        int best = 0x7FFFFFFF, bi = 0;
        for (int t2 = 0; t2 < m; ++t2)
          if (eqbuf[t2] < best) { best = eqbuf[t2]; bi = t2; }
        eqbuf[bi] = 0x7FFFFFFF;
        cand[count_gt + r] = best;
      }
    } else {
      int r = 0;
      for (int j = 0; j < NN_ && r < need_eq; ++j)
        if (mono_u(sv[j]) == T) cand[count_gt + (r++)] = j;
    }
  }
  __syncthreads();

  // ---- candidate values + angular locality mask ----
  const long dbase = (long)row * 3;
  const float dax = dirs_a[dbase + 0], day = dirs_a[dbase + 1],
              daz = dirs_a[dbase + 2];
  if (tid < KC_) {
    int j = cand[tid];
    cvalv[tid] = sv[j];
    const float* db = dirs_b + ((long)b * NN_ + j) * 3;
    float ca = dax * db[0] + day * db[1] + daz * db[2];
    int loc = (ca >= 0.96592582628906831f) ? 1 : 0;
    cmaskv[tid] = loc;
    if (loc) atomicAdd(&ecnt, 1);
  }
  __syncthreads();

  // ---- fine top-16 + softmax, wave 0 only ----
  if (tid < 64) {
    const bool all = (ecnt == 0);
    float v0 = (all || cmaskv[tid]) ? cvalv[tid] : -INFINITY;
    float v1 = (all || cmaskv[tid + 64]) ? cvalv[tid + 64] : -INFINITY;
    int j0 = cand[tid], j1 = cand[tid + 64];
    const int elig = all ? KC_ : ecnt;
    const int nk = elig < KF_ ? elig : KF_;
    if (tid == 0) nkeep_s = nk;
    for (int r = 0; r < nk; ++r) {
      float bvv; int bj; int bs;
      if (v1 > v0 || (v1 == v0 && j1 < j0)) { bvv = v1; bj = j1; bs = tid + 64; }
      else { bvv = v0; bj = j0; bs = tid; }
#pragma unroll
      for (int off = 32; off > 0; off >>= 1) {
        float ov = __shfl_down(bvv, off);
        int oj = __shfl_down(bj, off);
        int os = __shfl_down(bs, off);
        if (ov > bvv || (ov == bvv && oj < bj)) { bvv = ov; bj = oj; bs = os; }
      }
      bvv = __shfl(bvv, 0); bj = __shfl(bj, 0); bs = __shfl(bs, 0);
      if (tid == 0) { outj[r] = bj; outp[r] = bvv; }
      if (bs == tid) v0 = -INFINITY;
      if (bs == tid + 64) v1 = -INFINITY;
    }
    if (tid == 0) {
      float mx = -INFINITY;
      for (int r = 0; r < nk; ++r) mx = fmaxf(mx, outp[r] / 0.07f);
      float e[KF_];
      float ssum = 0.f;
      for (int r = 0; r < nk; ++r) {
        e[r] = expf(outp[r] / 0.07f - mx);
        ssum += e[r];
      }
      float s2 = 0.f;
      for (int r = 0; r < nk; ++r) { e[r] = e[r] / ssum; s2 += e[r]; }
      float inv = 1.0f / (s2 + 1e-8f);
      for (int r = 0; r < nk; ++r) outp[r] = e[r] * inv;
    }
  }
  __syncthreads();

  for (int i = tid; i < NN_; i += 256) sv[i] = 0.f;
  __syncthreads();
  if (tid < nkeep_s) sv[outj[tid]] = outp[tid];
  __syncthreads();
  for (int i = tid; i < NN_ / 4; i += 256)
    *(float4*)(prow + (i << 2)) = *(const float4*)&sv[i << 2];
}

extern "C" void kernel_launch(void* const* d_in, const int* in_sizes, int n_in,
                              void* d_out, int out_size, void* d_ws, size_t ws_size,
                              hipStream_t stream) {
  (void)in_sizes; (void)n_in; (void)out_size; (void)ws_size;
  const float* feat_a = (const float*)d_in[0];
  const float* feat_b = (const float*)d_in[1];
  const float* dirs_a = (const float*)d_in[2];
  const float* dirs_b = (const float*)d_in[3];
  const float* Wq = (const float*)d_in[4];
  const float* bq = (const float*)d_in[5];
  const float* Wk = (const float*)d_in[6];
  const float* bk = (const float*)d_in[7];
  float* P = (float*)d_out;

  // ws: qh,ql,kh,kl (bf16 4096x256 each = 8 MB) + sim fp32 (33.6 MB) = 41.6 MB
  __hip_bfloat16* qh = (__hip_bfloat16*)d_ws;
  __hip_bfloat16* ql = qh + (long)2 * NN_ * CC_;
  __hip_bfloat16* kh = ql + (long)2 * NN_ * CC_;
  __hip_bfloat16* kl = kh + (long)2 * NN_ * CC_;
  float* sim = (float*)(kl + (long)2 * NN_ * CC_);

  proj_split_kernel<<<dim3(CC_ / 64, (2 * NN_) / 64, 2), 256, 0, stream>>>(
      feat_a, feat_b, Wq, bq, Wk, bk, qh, ql, kh, kl);

  sim_mfma_kernel<<<dim3(NN_ / 128, NN_ / 128, 2), 256, 0, stream>>>(
      qh, ql, kh, kl, sim);

  select_scatter_kernel<<<dim3(2 * NN_), 256, 0, stream>>>(sim, dirs_a, dirs_b, P);
}

// Round 3
// 167.316 us; speedup vs baseline: 1.4275x; 1.0927x over previous
//
#include <hip/hip_runtime.h>
#include <hip/hip_bf16.h>
#include <math.h>

#define NN_ 2048
#define CC_ 256
#define KC_ 128
#define KF_ 16
#define EQCAP 64

typedef __attribute__((ext_vector_type(8))) short short8;
typedef __attribute__((ext_vector_type(4))) float f32x4;

__device__ __forceinline__ unsigned int mono_u(float f) {
  unsigned int u = __float_as_uint(f);
  return (u & 0x80000000u) ? ~u : (u | 0x80000000u);
}
__device__ __forceinline__ float inv_mono(unsigned int m) {
  unsigned int u = (m & 0x80000000u) ? (m ^ 0x80000000u) : ~m;
  return __uint_as_float(u);
}

__device__ __forceinline__ void gload_lds16(const void* g, void* l) {
  __builtin_amdgcn_global_load_lds(
      (const __attribute__((address_space(1))) void*)g,
      (__attribute__((address_space(3))) void*)l, 16, 0, 0);
}

// Fused projection: z=0 -> q = feat_a@Wq^T+bq -> (qh,ql); z=1 -> k -> (kh,kl).
// 32x64 tile, BK=32, 1024 blocks (4/CU) for latency hiding.
__global__ __launch_bounds__(256) void proj_split_kernel(
    const float* __restrict__ fa, const float* __restrict__ fb,
    const float* __restrict__ Wq, const float* __restrict__ bq,
    const float* __restrict__ Wk, const float* __restrict__ bk,
    __hip_bfloat16* __restrict__ qh, __hip_bfloat16* __restrict__ ql,
    __hip_bfloat16* __restrict__ kh, __hip_bfloat16* __restrict__ kl)
{
  __shared__ float As2[32][32];  // [k][m]
  __shared__ float Bs[32][64];   // [k][n]
  const int z = blockIdx.z;
  const float* A = z ? fb : fa;
  const float* W = z ? Wk : Wq;
  const float* bias = z ? bk : bq;
  __hip_bfloat16* oh = z ? kh : qh;
  __hip_bfloat16* ol = z ? kl : ql;

  const int m0 = blockIdx.y * 32, n0 = blockIdx.x * 64;
  const int tid = threadIdx.x;
  const int tx = tid & 15, ty = tid >> 4;
  const int r = tid >> 3, c4 = (tid & 7) << 2;
  float acc[2][4] = {};
  for (int kb = 0; kb < CC_; kb += 32) {
    float4 va = *(const float4*)(A + (long)(m0 + r) * CC_ + kb + c4);
    As2[c4 + 0][r] = va.x; As2[c4 + 1][r] = va.y;
    As2[c4 + 2][r] = va.z; As2[c4 + 3][r] = va.w;
    float4 vb0 = *(const float4*)(W + (long)(n0 + r) * CC_ + kb + c4);
    Bs[c4 + 0][r] = vb0.x; Bs[c4 + 1][r] = vb0.y;
    Bs[c4 + 2][r] = vb0.z; Bs[c4 + 3][r] = vb0.w;
    float4 vb1 = *(const float4*)(W + (long)(n0 + r + 32) * CC_ + kb + c4);
    Bs[c4 + 0][r + 32] = vb1.x; Bs[c4 + 1][r + 32] = vb1.y;
    Bs[c4 + 2][r + 32] = vb1.z; Bs[c4 + 3][r + 32] = vb1.w;
    __syncthreads();
#pragma unroll
    for (int kk = 0; kk < 32; ++kk) {
      float a0 = As2[kk][(ty << 1)];
      float a1 = As2[kk][(ty << 1) + 1];
      float4 bv = *(const float4*)&Bs[kk][tx << 2];
      acc[0][0] += a0 * bv.x; acc[0][1] += a0 * bv.y;
      acc[0][2] += a0 * bv.z; acc[0][3] += a0 * bv.w;
      acc[1][0] += a1 * bv.x; acc[1][1] += a1 * bv.y;
      acc[1][2] += a1 * bv.z; acc[1][3] += a1 * bv.w;
    }
    __syncthreads();
  }
  float bv4[4];
#pragma unroll
  for (int j = 0; j < 4; ++j) bv4[j] = bias[n0 + (tx << 2) + j];
#pragma unroll
  for (int i = 0; i < 2; ++i) {
    int m = m0 + (ty << 1) + i;
    __hip_bfloat16 hv[4], lv[4];
#pragma unroll
    for (int j = 0; j < 4; ++j) {
      float v = acc[i][j] + bv4[j];
      __hip_bfloat16 h = __float2bfloat16(v);  // RNE
      hv[j] = h;
      lv[j] = __float2bfloat16(v - __bfloat162float(h));
    }
    long base = (long)m * CC_ + n0 + (tx << 2);
    *(uint2*)(oh + base) = *(const uint2*)hv;
    *(uint2*)(ol + base) = *(const uint2*)lv;
  }
}

// sim[z] = qh@kh^T + qh@kl^T + ql@kh^T  (fp32-accurate split-bf16 product)
// 128x128 block tile, 4 waves x (4x4) mfma_f32_16x16x32_bf16, BK=32,
// global_load_lds width-16 staging, XOR chunk-swizzled LDS tile. (unchanged)
__global__ __launch_bounds__(256) void sim_mfma_kernel(
    const __hip_bfloat16* __restrict__ qh, const __hip_bfloat16* __restrict__ ql,
    const __hip_bfloat16* __restrict__ kh, const __hip_bfloat16* __restrict__ kl,
    float* __restrict__ sim)
{
  __shared__ short As[128 * 32];
  __shared__ short Bs[128 * 32];
  const int z = blockIdx.z;
  const long off = (long)z * NN_ * CC_;
  const __hip_bfloat16* Aseg[3] = {qh + off, qh + off, ql + off};
  const __hip_bfloat16* Bseg[3] = {kh + off, kl + off, kh + off};
  const int m0 = blockIdx.y * 128, n0 = blockIdx.x * 128;
  const int tid = threadIdx.x;
  const int lane = tid & 63, wave = tid >> 6;
  const int wm = (wave & 1) << 6, wn = (wave >> 1) << 6;
  const int fm = lane & 15, quad = lane >> 4;

  const int r0 = tid >> 2, r1 = r0 + 64;
  const int c0 = (((tid & 3) ^ ((r0 >> 1) & 3)) << 3);
  const int c1 = (((tid & 3) ^ ((r1 >> 1) & 3)) << 3);
  short* lA0 = As + (long)tid * 8;
  short* lA1 = As + ((long)tid + 256) * 8;
  short* lB0 = Bs + (long)tid * 8;
  short* lB1 = Bs + ((long)tid + 256) * 8;
  const long gA0 = (long)(m0 + r0) * CC_ + c0;
  const long gA1 = (long)(m0 + r1) * CC_ + c1;
  const long gB0 = (long)(n0 + r0) * CC_ + c0;
  const long gB1 = (long)(n0 + r1) * CC_ + c1;

  f32x4 acc[4][4];
#pragma unroll
  for (int i = 0; i < 4; ++i)
#pragma unroll
    for (int j = 0; j < 4; ++j)
      acc[i][j] = (f32x4){0.f, 0.f, 0.f, 0.f};

  for (int s = 0; s < 3; ++s) {
    const __hip_bfloat16* Ap = Aseg[s];
    const __hip_bfloat16* Bp = Bseg[s];
    for (int kb = 0; kb < CC_; kb += 32) {
      gload_lds16(Ap + gA0 + kb, lA0);
      gload_lds16(Ap + gA1 + kb, lA1);
      gload_lds16(Bp + gB0 + kb, lB0);
      gload_lds16(Bp + gB1 + kb, lB1);
      __syncthreads();
      short8 af[4], bf[4];
#pragma unroll
      for (int t = 0; t < 4; ++t) {
        int m = wm + (t << 4) + fm;
        af[t] = *(const short8*)&As[((m << 2) + (quad ^ ((m >> 1) & 3))) << 3];
        int n = wn + (t << 4) + fm;
        bf[t] = *(const short8*)&Bs[((n << 2) + (quad ^ ((n >> 1) & 3))) << 3];
      }
#pragma unroll
      for (int mi = 0; mi < 4; ++mi)
#pragma unroll
        for (int ni = 0; ni < 4; ++ni)
          acc[mi][ni] = __builtin_amdgcn_mfma_f32_16x16x32_bf16(
              af[mi], bf[ni], acc[mi][ni], 0, 0, 0);
      __syncthreads();
    }
  }

  float* Cp = sim + (long)z * NN_ * NN_;
#pragma unroll
  for (int mi = 0; mi < 4; ++mi) {
#pragma unroll
    for (int ni = 0; ni < 4; ++ni) {
      int m = m0 + wm + (mi << 4) + (quad << 2);
      int n = n0 + wn + (ni << 4) + fm;
      float* p = Cp + (long)m * NN_ + n;
      p[0] = acc[mi][ni][0];
      p[NN_] = acc[mi][ni][1];
      p[2 * NN_] = acc[mi][ni][2];
      p[3 * NN_] = acc[mi][ni][3];
    }
  }
}

// One WAVE per row, zero barriers. Wave-private LDS regions; DS ops from one
// wave complete in order (FIFO), so write->read within the wave needs no
// __syncthreads. Radix select top-128 (jax tie semantics), angular mask with
// all-true fallback, fine top-16 (value desc, idx asc), softmax, writeback.
__global__ __launch_bounds__(256) void select_scatter_kernel(
    const float* __restrict__ sim, const float* __restrict__ dirs_a,
    const float* __restrict__ dirs_b, float* __restrict__ P)
{
  const int wave = threadIdx.x >> 6;
  const int lane = threadIdx.x & 63;
  const int row = (blockIdx.x << 2) | wave;  // grid = 1024, 4 rows/block
  const int b = row >> 11;
  const float* srow = sim + (long)row * NN_;
  float* prow = P + (long)row * NN_;

  __shared__ unsigned int hist_s[4][256];
  __shared__ unsigned int ckey_s[4][KC_];
  __shared__ int cidx_s[4][KC_];
  __shared__ int eq_s[4][EQCAP];
  __shared__ float outp_s[4][KF_];
  __shared__ int outj_s[4][KF_];
  __shared__ float rowbuf_s[4][1024];
  __shared__ int cnt_s[4][2];

  unsigned int* hist = hist_s[wave];
  unsigned int* ckey = ckey_s[wave];
  int* cidx = cidx_s[wave];
  int* eqb = eq_s[wave];
  float* outp = outp_s[wave];
  int* outj = outj_s[wave];
  float* rowbuf = rowbuf_s[wave];
  int* cnt = cnt_s[wave];

  // row -> 32 monotone keys per lane (coalesced float4 loads)
  unsigned int key[32];
#pragma unroll
  for (int c = 0; c < 8; ++c) {
    float4 v = *(const float4*)(srow + (c << 8) + (lane << 2));
    key[(c << 2) + 0] = mono_u(v.x);
    key[(c << 2) + 1] = mono_u(v.y);
    key[(c << 2) + 2] = mono_u(v.z);
    key[(c << 2) + 3] = mono_u(v.w);
  }

  // ---- radix select: key of the 128th largest ----
  unsigned int prefix = 0u, pmask = 0u;
  int need = KC_;
  for (int pass = 0; pass < 4; ++pass) {
    const int sh = 24 - (pass << 3);
    uint4 z4; z4.x = z4.y = z4.z = z4.w = 0u;
    *(uint4*)&hist[lane << 2] = z4;
#pragma unroll
    for (int i = 0; i < 32; ++i) {
      unsigned int u = key[i];
      if ((u & pmask) == prefix) atomicAdd(&hist[(u >> sh) & 255u], 1u);
    }
    uint4 h = *(const uint4*)&hist[lane << 2];
    unsigned int s3 = h.w, s2 = h.z + s3, s1 = h.y + s2, s0 = h.x + s1;
    unsigned int tot = s0, incl = tot;
#pragma unroll
    for (int off = 1; off < 64; off <<= 1) {
      unsigned int y = __shfl_down(incl, off);
      incl += (lane + off < 64) ? y : 0u;
    }
    const unsigned int excl = incl - tot;
    unsigned int geq[4] = {s0 + excl, s1 + excl, s2 + excl, s3 + excl};
    unsigned int gt[4] = {s1 + excl, s2 + excl, s3 + excl, excl};
    int fbin = -1;
    unsigned int fgt = 0u;
#pragma unroll
    for (int i = 0; i < 4; ++i)
      if (fbin < 0 && geq[i] >= (unsigned)need && gt[i] < (unsigned)need) {
        fbin = (lane << 2) + i;
        fgt = gt[i];
      }
    unsigned long long mb = __ballot(fbin >= 0);
    int src = __ffsll(mb) - 1;
    int selbin = __shfl(fbin, src);
    unsigned int gtv = __shfl(fgt, src);
    prefix |= ((unsigned)(selbin & 255)) << sh;
    pmask |= 0xFFu << sh;
    need -= (int)gtv;
  }
  const unsigned int T = prefix;
  const int need_eq = need;
  const int count_gt = KC_ - need_eq;

  // ---- collect candidates ----
  if (lane == 0) { cnt[0] = 0; cnt[1] = 0; }
#pragma unroll
  for (int i = 0; i < 32; ++i) {
    unsigned int u = key[i];
    int col = ((i >> 2) << 8) + (lane << 2) + (i & 3);
    if (u > T) {
      int p = atomicAdd(&cnt[0], 1);
      ckey[p] = u;
      cidx[p] = col;
    } else if (u == T) {
      int p = atomicAdd(&cnt[1], 1);
      if (p < EQCAP) eqb[p] = col;
    }
  }
  int neq = cnt[1];
  if (lane == 0) {
    if (neq <= EQCAP) {  // typical: neq == 1
      for (int r = 0; r < need_eq; ++r) {
        int best = 0x7FFFFFFF, bi = 0;
        for (int t2 = 0; t2 < neq; ++t2)
          if (eqb[t2] < best) { best = eqb[t2]; bi = t2; }
        eqb[bi] = 0x7FFFFFFF;
        ckey[count_gt + r] = T;
        cidx[count_gt + r] = best;
      }
    } else {  // pathological mass-tie: rescan row in index order
      int r2 = 0;
      for (int j = 0; j < NN_ && r2 < need_eq; ++j)
        if (mono_u(srow[j]) == T) {
          ckey[count_gt + r2] = T;
          cidx[count_gt + r2] = j;
          ++r2;
        }
    }
  }

  // ---- angular mask (2 candidates/lane) ----
  const long dbase = (long)row * 3;
  const float dax = dirs_a[dbase + 0], day = dirs_a[dbase + 1],
              daz = dirs_a[dbase + 2];
  int j0 = cidx[lane], j1 = cidx[lane + 64];
  float va0 = inv_mono(ckey[lane]), va1 = inv_mono(ckey[lane + 64]);
  const float* db0 = dirs_b + ((long)(b << 11) + j0) * 3;
  float ca0 = dax * db0[0] + day * db0[1] + daz * db0[2];
  const float* db1 = dirs_b + ((long)(b << 11) + j1) * 3;
  float ca1 = dax * db1[0] + day * db1[1] + daz * db1[2];
  bool lm0 = ca0 >= 0.96592582628906831f;
  bool lm1 = ca1 >= 0.96592582628906831f;
  int ecnt = __popcll(__ballot(lm0)) + __popcll(__ballot(lm1));
  const bool all = (ecnt == 0);
  float v0 = (all || lm0) ? va0 : -INFINITY;
  float v1 = (all || lm1) ? va1 : -INFINITY;
  const int elig = all ? KC_ : ecnt;
  const int nk = elig < KF_ ? elig : KF_;

  // ---- fine top-16: iterative wave-wide argmax extraction ----
  for (int r = 0; r < nk; ++r) {
    float bvv; int bj, bs;
    if (v1 > v0 || (v1 == v0 && j1 < j0)) { bvv = v1; bj = j1; bs = lane + 64; }
    else { bvv = v0; bj = j0; bs = lane; }
#pragma unroll
    for (int off = 32; off > 0; off >>= 1) {
      float ov = __shfl_down(bvv, off);
      int oj = __shfl_down(bj, off);
      int os = __shfl_down(bs, off);
      if (ov > bvv || (ov == bvv && oj < bj)) { bvv = ov; bj = oj; bs = os; }
    }
    bvv = __shfl(bvv, 0); bj = __shfl(bj, 0); bs = __shfl(bs, 0);
    if (lane == 0) { outj[r] = bj; outp[r] = bvv; }
    if (bs == lane) v0 = -INFINITY;
    if (bs == lane + 64) v1 = -INFINITY;
  }

  // ---- softmax over kept logits (parallel over 16 lanes) ----
  const float invT = 1.0f / 0.07f;
  float mxl = outp[0] * invT;  // extraction is descending -> slot 0 is max
  float e = 0.f;
  int myj = 0;
  if (lane < nk) {
    e = __expf(outp[lane] * invT - mxl);
    myj = outj[lane];
  }
  float ssum = e;
#pragma unroll
  for (int off = 32; off > 0; off >>= 1) ssum += __shfl_xor(ssum, off);
  float pr = e / ssum;
  float s2 = pr;
#pragma unroll
  for (int off = 32; off > 0; off >>= 1) s2 += __shfl_xor(s2, off);
  const float outv = pr * (1.0f / (s2 + 1e-8f));

  // ---- zero + scatter + coalesced writeback, two 4KB halves ----
#pragma unroll
  for (int h = 0; h < 2; ++h) {
    float4 zf; zf.x = zf.y = zf.z = zf.w = 0.f;
#pragma unroll
    for (int q = 0; q < 4; ++q)
      *(float4*)&rowbuf[(q << 8) + (lane << 2)] = zf;
    if (lane < nk && (myj >> 10) == h) rowbuf[myj & 1023] = outv;
#pragma unroll
    for (int q = 0; q < 4; ++q) {
      float4 v = *(const float4*)&rowbuf[(q << 8) + (lane << 2)];
      *(float4*)(prow + (h << 10) + (q << 8) + (lane << 2)) = v;
    }
  }
}

extern "C" void kernel_launch(void* const* d_in, const int* in_sizes, int n_in,
                              void* d_out, int out_size, void* d_ws, size_t ws_size,
                              hipStream_t stream) {
  (void)in_sizes; (void)n_in; (void)out_size; (void)ws_size;
  const float* feat_a = (const float*)d_in[0];
  const float* feat_b = (const float*)d_in[1];
  const float* dirs_a = (const float*)d_in[2];
  const float* dirs_b = (const float*)d_in[3];
  const float* Wq = (const float*)d_in[4];
  const float* bq = (const float*)d_in[5];
  const float* Wk = (const float*)d_in[6];
  const float* bk = (const float*)d_in[7];
  float* P = (float*)d_out;

  __hip_bfloat16* qh = (__hip_bfloat16*)d_ws;
  __hip_bfloat16* ql = qh + (long)2 * NN_ * CC_;
  __hip_bfloat16* kh = ql + (long)2 * NN_ * CC_;
  __hip_bfloat16* kl = kh + (long)2 * NN_ * CC_;
  float* sim = (float*)(kl + (long)2 * NN_ * CC_);

  proj_split_kernel<<<dim3(CC_ / 64, (2 * NN_) / 32, 2), 256, 0, stream>>>(
      feat_a, feat_b, Wq, bq, Wk, bk, qh, ql, kh, kl);

  sim_mfma_kernel<<<dim3(NN_ / 128, NN_ / 128, 2), 256, 0, stream>>>(
      qh, ql, kh, kl, sim);

  select_scatter_kernel<<<dim3((2 * NN_) / 4), 256, 0, stream>>>(
      sim, dirs_a, dirs_b, P);
}

// Round 4
// 143.337 us; speedup vs baseline: 1.6664x; 1.1673x over previous
//
#include <hip/hip_runtime.h>
#include <hip/hip_bf16.h>
#include <math.h>

#define NN_ 2048
#define CC_ 256
#define KC_ 128
#define KF_ 16
#define EQCAP 64

typedef __attribute__((ext_vector_type(8))) short short8;
typedef __attribute__((ext_vector_type(4))) float f32x4;

__device__ __forceinline__ unsigned int mono_u(float f) {
  unsigned int u = __float_as_uint(f);
  return (u & 0x80000000u) ? ~u : (u | 0x80000000u);
}
__device__ __forceinline__ float inv_mono(unsigned int m) {
  unsigned int u = (m & 0x80000000u) ? (m ^ 0x80000000u) : ~m;
  return __uint_as_float(u);
}

__device__ __forceinline__ void gload_lds16(const void* g, void* l) {
  __builtin_amdgcn_global_load_lds(
      (const __attribute__((address_space(1))) void*)g,
      (__attribute__((address_space(3))) void*)l, 16, 0, 0);
}

__device__ __forceinline__ unsigned short bf16_bits(float v) {
  __hip_bfloat16 h = __float2bfloat16(v);  // RNE
  return *(unsigned short*)&h;
}
__device__ __forceinline__ float bf16_val(unsigned short u) {
  __hip_bfloat16 h = *(__hip_bfloat16*)&u;
  return __bfloat162float(h);
}

// Projection via split-bf16 MFMA (3 terms), fp32->h/l split fused into LDS
// staging. 64x64 tile, K=256, z folded into blockIdx.y (rows >=4096 -> k-side).
__global__ __launch_bounds__(256) void proj_mfma_kernel(
    const float* __restrict__ fa, const float* __restrict__ fb,
    const float* __restrict__ Wq, const float* __restrict__ bq,
    const float* __restrict__ Wk, const float* __restrict__ bk,
    __hip_bfloat16* __restrict__ qh, __hip_bfloat16* __restrict__ ql,
    __hip_bfloat16* __restrict__ kh, __hip_bfloat16* __restrict__ kl)
{
  __shared__ short Ah[64 * 32], Al[64 * 32], Bh[64 * 32], Bl[64 * 32];  // 16 KB
  const int m0 = blockIdx.y * 64;   // 0..8128 over both batches+sides
  const int z = m0 >> 12;           // rows >= 4096 -> k projection
  const int mloc = m0 & 4095;
  const float* A = z ? fb : fa;
  const float* W = z ? Wk : Wq;
  const float* bias = z ? bk : bq;
  __hip_bfloat16* oh = z ? kh : qh;
  __hip_bfloat16* ol = z ? kl : ql;
  const int n0 = blockIdx.x * 64;
  const int tid = threadIdx.x;
  const int lane = tid & 63, wave = tid >> 6;
  const int wm = (wave & 1) << 5, wn = (wave >> 1) << 5;
  const int fm = lane & 15, quad = lane >> 4;

  const int r = tid >> 3;           // 0..31
  const int r2 = r + 32;
  const int c4 = (tid & 7) << 2;    // 0,4,...,28
  const int ck = c4 >> 3;
  const int soff = c4 & 7;          // 0 or 4 shorts within the 8-short slot
  const int iA0 = (((r << 2) + (ck ^ ((r >> 1) & 3))) << 3) + soff;
  const int iA1 = (((r2 << 2) + (ck ^ ((r2 >> 1) & 3))) << 3) + soff;

  f32x4 acc[2][2];
#pragma unroll
  for (int i = 0; i < 2; ++i)
#pragma unroll
    for (int j = 0; j < 2; ++j) acc[i][j] = (f32x4){0.f, 0.f, 0.f, 0.f};

  for (int kb = 0; kb < CC_; kb += 32) {
    float4 va0 = *(const float4*)(A + (long)(mloc + r) * CC_ + kb + c4);
    float4 va1 = *(const float4*)(A + (long)(mloc + r2) * CC_ + kb + c4);
    float4 vb0 = *(const float4*)(W + (long)(n0 + r) * CC_ + kb + c4);
    float4 vb1 = *(const float4*)(W + (long)(n0 + r2) * CC_ + kb + c4);
    __syncthreads();  // previous iter's frag reads done before overwrite
    {
      const float* pv;
      float4 vv;
      // A row r
      vv = va0; pv = (const float*)&vv;
      uint2 hu, lu;
      unsigned short h0 = bf16_bits(pv[0]), h1 = bf16_bits(pv[1]),
                     h2 = bf16_bits(pv[2]), h3 = bf16_bits(pv[3]);
      hu.x = (unsigned)h0 | ((unsigned)h1 << 16);
      hu.y = (unsigned)h2 | ((unsigned)h3 << 16);
      lu.x = (unsigned)bf16_bits(pv[0] - bf16_val(h0)) |
             ((unsigned)bf16_bits(pv[1] - bf16_val(h1)) << 16);
      lu.y = (unsigned)bf16_bits(pv[2] - bf16_val(h2)) |
             ((unsigned)bf16_bits(pv[3] - bf16_val(h3)) << 16);
      *(uint2*)&Ah[iA0] = hu; *(uint2*)&Al[iA0] = lu;
      // A row r+32
      vv = va1; pv = (const float*)&vv;
      h0 = bf16_bits(pv[0]); h1 = bf16_bits(pv[1]);
      h2 = bf16_bits(pv[2]); h3 = bf16_bits(pv[3]);
      hu.x = (unsigned)h0 | ((unsigned)h1 << 16);
      hu.y = (unsigned)h2 | ((unsigned)h3 << 16);
      lu.x = (unsigned)bf16_bits(pv[0] - bf16_val(h0)) |
             ((unsigned)bf16_bits(pv[1] - bf16_val(h1)) << 16);
      lu.y = (unsigned)bf16_bits(pv[2] - bf16_val(h2)) |
             ((unsigned)bf16_bits(pv[3] - bf16_val(h3)) << 16);
      *(uint2*)&Ah[iA1] = hu; *(uint2*)&Al[iA1] = lu;
      // B row r
      vv = vb0; pv = (const float*)&vv;
      h0 = bf16_bits(pv[0]); h1 = bf16_bits(pv[1]);
      h2 = bf16_bits(pv[2]); h3 = bf16_bits(pv[3]);
      hu.x = (unsigned)h0 | ((unsigned)h1 << 16);
      hu.y = (unsigned)h2 | ((unsigned)h3 << 16);
      lu.x = (unsigned)bf16_bits(pv[0] - bf16_val(h0)) |
             ((unsigned)bf16_bits(pv[1] - bf16_val(h1)) << 16);
      lu.y = (unsigned)bf16_bits(pv[2] - bf16_val(h2)) |
             ((unsigned)bf16_bits(pv[3] - bf16_val(h3)) << 16);
      *(uint2*)&Bh[iA0] = hu; *(uint2*)&Bl[iA0] = lu;
      // B row r+32
      vv = vb1; pv = (const float*)&vv;
      h0 = bf16_bits(pv[0]); h1 = bf16_bits(pv[1]);
      h2 = bf16_bits(pv[2]); h3 = bf16_bits(pv[3]);
      hu.x = (unsigned)h0 | ((unsigned)h1 << 16);
      hu.y = (unsigned)h2 | ((unsigned)h3 << 16);
      lu.x = (unsigned)bf16_bits(pv[0] - bf16_val(h0)) |
             ((unsigned)bf16_bits(pv[1] - bf16_val(h1)) << 16);
      lu.y = (unsigned)bf16_bits(pv[2] - bf16_val(h2)) |
             ((unsigned)bf16_bits(pv[3] - bf16_val(h3)) << 16);
      *(uint2*)&Bh[iA1] = hu; *(uint2*)&Bl[iA1] = lu;
    }
    __syncthreads();
    short8 afh[2], afl[2], bfh[2], bfl[2];
#pragma unroll
    for (int t = 0; t < 2; ++t) {
      int m = wm + (t << 4) + fm;
      int sa = ((m << 2) + (quad ^ ((m >> 1) & 3))) << 3;
      afh[t] = *(const short8*)&Ah[sa];
      afl[t] = *(const short8*)&Al[sa];
      int n = wn + (t << 4) + fm;
      int sb = ((n << 2) + (quad ^ ((n >> 1) & 3))) << 3;
      bfh[t] = *(const short8*)&Bh[sb];
      bfl[t] = *(const short8*)&Bl[sb];
    }
#pragma unroll
    for (int mi = 0; mi < 2; ++mi)
#pragma unroll
      for (int ni = 0; ni < 2; ++ni) {
        acc[mi][ni] = __builtin_amdgcn_mfma_f32_16x16x32_bf16(
            afh[mi], bfh[ni], acc[mi][ni], 0, 0, 0);
        acc[mi][ni] = __builtin_amdgcn_mfma_f32_16x16x32_bf16(
            afh[mi], bfl[ni], acc[mi][ni], 0, 0, 0);
        acc[mi][ni] = __builtin_amdgcn_mfma_f32_16x16x32_bf16(
            afl[mi], bfh[ni], acc[mi][ni], 0, 0, 0);
      }
  }

  // epilogue: + bias, RNE split to (h,l), store. C layout: col=lane&15,
  // row = quad*4 + reg.
#pragma unroll
  for (int mi = 0; mi < 2; ++mi)
#pragma unroll
    for (int ni = 0; ni < 2; ++ni) {
      int nn = n0 + wn + (ni << 4) + fm;
      float bval = bias[nn];
      int mrow = mloc + wm + (mi << 4) + (quad << 2);
#pragma unroll
      for (int reg = 0; reg < 4; ++reg) {
        float v = acc[mi][ni][reg] + bval;
        __hip_bfloat16 h = __float2bfloat16(v);
        long idx = (long)(mrow + reg) * CC_ + nn;
        oh[idx] = h;
        ol[idx] = __float2bfloat16(v - __bfloat162float(h));
      }
    }
}

// sim[z] = qh@kh^T + qh@kl^T + ql@kh^T, 3 terms INTERLEAVED in one K-loop:
// per 32-k chunk stage Ah/Al/Bh/Bl (32 KB LDS), 48 MFMA per barrier pair.
__global__ __launch_bounds__(256) void sim_mfma_kernel(
    const __hip_bfloat16* __restrict__ qh, const __hip_bfloat16* __restrict__ ql,
    const __hip_bfloat16* __restrict__ kh, const __hip_bfloat16* __restrict__ kl,
    float* __restrict__ sim)
{
  __shared__ short Ah[128 * 32], Al[128 * 32], Bh[128 * 32], Bl[128 * 32];
  const int z = blockIdx.z;
  const long off = (long)z * NN_ * CC_;
  const int m0 = blockIdx.y * 128, n0 = blockIdx.x * 128;
  const int tid = threadIdx.x;
  const int lane = tid & 63, wave = tid >> 6;
  const int wm = (wave & 1) << 6, wn = (wave >> 1) << 6;
  const int fm = lane & 15, quad = lane >> 4;

  const int r0 = tid >> 2, r1 = r0 + 64;
  const int c0 = (((tid & 3) ^ ((r0 >> 1) & 3)) << 3);
  const int c1 = (((tid & 3) ^ ((r1 >> 1) & 3)) << 3);
  const long lo0 = (long)tid * 8, lo1 = ((long)tid + 256) * 8;
  const long gA0 = (long)(m0 + r0) * CC_ + c0 + off;
  const long gA1 = (long)(m0 + r1) * CC_ + c1 + off;
  const long gB0 = (long)(n0 + r0) * CC_ + c0 + off;
  const long gB1 = (long)(n0 + r1) * CC_ + c1 + off;

  f32x4 acc[4][4];
#pragma unroll
  for (int i = 0; i < 4; ++i)
#pragma unroll
    for (int j = 0; j < 4; ++j) acc[i][j] = (f32x4){0.f, 0.f, 0.f, 0.f};

  for (int kb = 0; kb < CC_; kb += 32) {
    gload_lds16(qh + gA0 + kb, Ah + lo0);
    gload_lds16(qh + gA1 + kb, Ah + lo1);
    gload_lds16(ql + gA0 + kb, Al + lo0);
    gload_lds16(ql + gA1 + kb, Al + lo1);
    gload_lds16(kh + gB0 + kb, Bh + lo0);
    gload_lds16(kh + gB1 + kb, Bh + lo1);
    gload_lds16(kl + gB0 + kb, Bl + lo0);
    gload_lds16(kl + gB1 + kb, Bl + lo1);
    __syncthreads();
    short8 afh[4], afl[4], bfh[4], bfl[4];
#pragma unroll
    for (int t = 0; t < 4; ++t) {
      int m = wm + (t << 4) + fm;
      int sa = ((m << 2) + (quad ^ ((m >> 1) & 3))) << 3;
      afh[t] = *(const short8*)&Ah[sa];
      afl[t] = *(const short8*)&Al[sa];
      int n = wn + (t << 4) + fm;
      int sb = ((n << 2) + (quad ^ ((n >> 1) & 3))) << 3;
      bfh[t] = *(const short8*)&Bh[sb];
      bfl[t] = *(const short8*)&Bl[sb];
    }
#pragma unroll
    for (int mi = 0; mi < 4; ++mi)
#pragma unroll
      for (int ni = 0; ni < 4; ++ni) {
        acc[mi][ni] = __builtin_amdgcn_mfma_f32_16x16x32_bf16(
            afh[mi], bfh[ni], acc[mi][ni], 0, 0, 0);
        acc[mi][ni] = __builtin_amdgcn_mfma_f32_16x16x32_bf16(
            afh[mi], bfl[ni], acc[mi][ni], 0, 0, 0);
        acc[mi][ni] = __builtin_amdgcn_mfma_f32_16x16x32_bf16(
            afl[mi], bfh[ni], acc[mi][ni], 0, 0, 0);
      }
    __syncthreads();
  }

  float* Cp = sim + (long)z * NN_ * NN_;
#pragma unroll
  for (int mi = 0; mi < 4; ++mi) {
#pragma unroll
    for (int ni = 0; ni < 4; ++ni) {
      int m = m0 + wm + (mi << 4) + (quad << 2);
      int n = n0 + wn + (ni << 4) + fm;
      float* p = Cp + (long)m * NN_ + n;
      p[0] = acc[mi][ni][0];
      p[NN_] = acc[mi][ni][1];
      p[2 * NN_] = acc[mi][ni][2];
      p[3 * NN_] = acc[mi][ni][3];
    }
  }
}

// One WAVE per row, zero barriers (unchanged from round 3).
__global__ __launch_bounds__(256) void select_scatter_kernel(
    const float* __restrict__ sim, const float* __restrict__ dirs_a,
    const float* __restrict__ dirs_b, float* __restrict__ P)
{
  const int wave = threadIdx.x >> 6;
  const int lane = threadIdx.x & 63;
  const int row = (blockIdx.x << 2) | wave;
  const int b = row >> 11;
  const float* srow = sim + (long)row * NN_;
  float* prow = P + (long)row * NN_;

  __shared__ unsigned int hist_s[4][256];
  __shared__ unsigned int ckey_s[4][KC_];
  __shared__ int cidx_s[4][KC_];
  __shared__ int eq_s[4][EQCAP];
  __shared__ float outp_s[4][KF_];
  __shared__ int outj_s[4][KF_];
  __shared__ float rowbuf_s[4][1024];
  __shared__ int cnt_s[4][2];

  unsigned int* hist = hist_s[wave];
  unsigned int* ckey = ckey_s[wave];
  int* cidx = cidx_s[wave];
  int* eqb = eq_s[wave];
  float* outp = outp_s[wave];
  int* outj = outj_s[wave];
  float* rowbuf = rowbuf_s[wave];
  int* cnt = cnt_s[wave];

  unsigned int key[32];
#pragma unroll
  for (int c = 0; c < 8; ++c) {
    float4 v = *(const float4*)(srow + (c << 8) + (lane << 2));
    key[(c << 2) + 0] = mono_u(v.x);
    key[(c << 2) + 1] = mono_u(v.y);
    key[(c << 2) + 2] = mono_u(v.z);
    key[(c << 2) + 3] = mono_u(v.w);
  }

  unsigned int prefix = 0u, pmask = 0u;
  int need = KC_;
  for (int pass = 0; pass < 4; ++pass) {
    const int sh = 24 - (pass << 3);
    uint4 z4; z4.x = z4.y = z4.z = z4.w = 0u;
    *(uint4*)&hist[lane << 2] = z4;
#pragma unroll
    for (int i = 0; i < 32; ++i) {
      unsigned int u = key[i];
      if ((u & pmask) == prefix) atomicAdd(&hist[(u >> sh) & 255u], 1u);
    }
    uint4 h = *(const uint4*)&hist[lane << 2];
    unsigned int s3 = h.w, s2 = h.z + s3, s1 = h.y + s2, s0 = h.x + s1;
    unsigned int tot = s0, incl = tot;
#pragma unroll
    for (int off = 1; off < 64; off <<= 1) {
      unsigned int y = __shfl_down(incl, off);
      incl += (lane + off < 64) ? y : 0u;
    }
    const unsigned int excl = incl - tot;
    unsigned int geq[4] = {s0 + excl, s1 + excl, s2 + excl, s3 + excl};
    unsigned int gt[4] = {s1 + excl, s2 + excl, s3 + excl, excl};
    int fbin = -1;
    unsigned int fgt = 0u;
#pragma unroll
    for (int i = 0; i < 4; ++i)
      if (fbin < 0 && geq[i] >= (unsigned)need && gt[i] < (unsigned)need) {
        fbin = (lane << 2) + i;
        fgt = gt[i];
      }
    unsigned long long mb = __ballot(fbin >= 0);
    int src = __ffsll(mb) - 1;
    int selbin = __shfl(fbin, src);
    unsigned int gtv = __shfl(fgt, src);
    prefix |= ((unsigned)(selbin & 255)) << sh;
    pmask |= 0xFFu << sh;
    need -= (int)gtv;
  }
  const unsigned int T = prefix;
  const int need_eq = need;
  const int count_gt = KC_ - need_eq;

  if (lane == 0) { cnt[0] = 0; cnt[1] = 0; }
#pragma unroll
  for (int i = 0; i < 32; ++i) {
    unsigned int u = key[i];
    int col = ((i >> 2) << 8) + (lane << 2) + (i & 3);
    if (u > T) {
      int p = atomicAdd(&cnt[0], 1);
      ckey[p] = u;
      cidx[p] = col;
    } else if (u == T) {
      int p = atomicAdd(&cnt[1], 1);
      if (p < EQCAP) eqb[p] = col;
    }
  }
  int neq = cnt[1];
  if (lane == 0) {
    if (neq <= EQCAP) {
      for (int r = 0; r < need_eq; ++r) {
        int best = 0x7FFFFFFF, bi = 0;
        for (int t2 = 0; t2 < neq; ++t2)
          if (eqb[t2] < best) { best = eqb[t2]; bi = t2; }
        eqb[bi] = 0x7FFFFFFF;
        ckey[count_gt + r] = T;
        cidx[count_gt + r] = best;
      }
    } else {
      int r2 = 0;
      for (int j = 0; j < NN_ && r2 < need_eq; ++j)
        if (mono_u(srow[j]) == T) {
          ckey[count_gt + r2] = T;
          cidx[count_gt + r2] = j;
          ++r2;
        }
    }
  }

  const long dbase = (long)row * 3;
  const float dax = dirs_a[dbase + 0], day = dirs_a[dbase + 1],
              daz = dirs_a[dbase + 2];
  int j0 = cidx[lane], j1 = cidx[lane + 64];
  float va0 = inv_mono(ckey[lane]), va1 = inv_mono(ckey[lane + 64]);
  const float* db0 = dirs_b + ((long)(b << 11) + j0) * 3;
  float ca0 = dax * db0[0] + day * db0[1] + daz * db0[2];
  const float* db1 = dirs_b + ((long)(b << 11) + j1) * 3;
  float ca1 = dax * db1[0] + day * db1[1] + daz * db1[2];
  bool lm0 = ca0 >= 0.96592582628906831f;
  bool lm1 = ca1 >= 0.96592582628906831f;
  int ecnt = __popcll(__ballot(lm0)) + __popcll(__ballot(lm1));
  const bool all = (ecnt == 0);
  float v0 = (all || lm0) ? va0 : -INFINITY;
  float v1 = (all || lm1) ? va1 : -INFINITY;
  const int elig = all ? KC_ : ecnt;
  const int nk = elig < KF_ ? elig : KF_;

  for (int r = 0; r < nk; ++r) {
    float bvv; int bj, bs;
    if (v1 > v0 || (v1 == v0 && j1 < j0)) { bvv = v1; bj = j1; bs = lane + 64; }
    else { bvv = v0; bj = j0; bs = lane; }
#pragma unroll
    for (int off = 32; off > 0; off >>= 1) {
      float ov = __shfl_down(bvv, off);
      int oj = __shfl_down(bj, off);
      int os = __shfl_down(bs, off);
      if (ov > bvv || (ov == bvv && oj < bj)) { bvv = ov; bj = oj; bs = os; }
    }
    bvv = __shfl(bvv, 0); bj = __shfl(bj, 0); bs = __shfl(bs, 0);
    if (lane == 0) { outj[r] = bj; outp[r] = bvv; }
    if (bs == lane) v0 = -INFINITY;
    if (bs == lane + 64) v1 = -INFINITY;
  }

  const float invT = 1.0f / 0.07f;
  float mxl = outp[0] * invT;
  float e = 0.f;
  int myj = 0;
  if (lane < nk) {
    e = __expf(outp[lane] * invT - mxl);
    myj = outj[lane];
  }
  float ssum = e;
#pragma unroll
  for (int off = 32; off > 0; off >>= 1) ssum += __shfl_xor(ssum, off);
  float pr = e / ssum;
  float s2 = pr;
#pragma unroll
  for (int off = 32; off > 0; off >>= 1) s2 += __shfl_xor(s2, off);
  const float outv = pr * (1.0f / (s2 + 1e-8f));

#pragma unroll
  for (int h = 0; h < 2; ++h) {
    float4 zf; zf.x = zf.y = zf.z = zf.w = 0.f;
#pragma unroll
    for (int q = 0; q < 4; ++q)
      *(float4*)&rowbuf[(q << 8) + (lane << 2)] = zf;
    if (lane < nk && (myj >> 10) == h) rowbuf[myj & 1023] = outv;
#pragma unroll
    for (int q = 0; q < 4; ++q) {
      float4 v = *(const float4*)&rowbuf[(q << 8) + (lane << 2)];
      *(float4*)(prow + (h << 10) + (q << 8) + (lane << 2)) = v;
    }
  }
}

extern "C" void kernel_launch(void* const* d_in, const int* in_sizes, int n_in,
                              void* d_out, int out_size, void* d_ws, size_t ws_size,
                              hipStream_t stream) {
  (void)in_sizes; (void)n_in; (void)out_size; (void)ws_size;
  const float* feat_a = (const float*)d_in[0];
  const float* feat_b = (const float*)d_in[1];
  const float* dirs_a = (const float*)d_in[2];
  const float* dirs_b = (const float*)d_in[3];
  const float* Wq = (const float*)d_in[4];
  const float* bq = (const float*)d_in[5];
  const float* Wk = (const float*)d_in[6];
  const float* bk = (const float*)d_in[7];
  float* P = (float*)d_out;

  __hip_bfloat16* qh = (__hip_bfloat16*)d_ws;
  __hip_bfloat16* ql = qh + (long)2 * NN_ * CC_;
  __hip_bfloat16* kh = ql + (long)2 * NN_ * CC_;
  __hip_bfloat16* kl = kh + (long)2 * NN_ * CC_;
  float* sim = (float*)(kl + (long)2 * NN_ * CC_);

  proj_mfma_kernel<<<dim3(CC_ / 64, (4 * NN_) / 64), 256, 0, stream>>>(
      feat_a, feat_b, Wq, bq, Wk, bk, qh, ql, kh, kl);

  sim_mfma_kernel<<<dim3(NN_ / 128, NN_ / 128, 2), 256, 0, stream>>>(
      qh, ql, kh, kl, sim);

  select_scatter_kernel<<<dim3((2 * NN_) / 4), 256, 0, stream>>>(
      sim, dirs_a, dirs_b, P);
}